// Round 1
// baseline (3003.082 us; speedup 1.0000x reference)
//
#include <hip/hip_runtime.h>
#include <hip/hip_bf16.h>

// Problem constants
#define NBL 6      // B*LEN
#define NC 64
#define NC3 192
#define NHW 4096   // 64*64
#define NDI 128
#define NNS 16
#define NDR 4
#define NK 4
#define NL 4096

// workspace offsets in floats
static const size_t F_XCAT  = 0;          // 6*192*4096 = 4,718,592
static const size_t F_ACT1  = 4718592;    // 4,718,592
static const size_t F_H1    = 9437184;    // 1,572,864
static const size_t F_ACT2  = 11010048;   // 1,572,864
static const size_t F_H2    = 12582912;   // 1,572,864
static const size_t F_DELTA = 0;          // 12,582,912 — aliases XCAT..ACT2 (dead by then)
static const size_t F_XRES  = 14155776;   // 1,572,864
static const size_t F_XXIN  = 15728640;   // 3,145,728
static const size_t F_Z     = 18874368;   // 3,145,728
static const size_t F_XXC   = 22020096;   // 3,145,728
static const size_t F_XDBL  = 25165824;   // 6*4*36*4096 = 3,538,944
static const size_t F_YS    = 28704768;   // 12,582,912
static const size_t F_YCOMB = 41287680;   // 3,145,728
static const size_t F_X1    = 44433408;   // 1,572,864
static const size_t F_X2    = 46006272;   // 1,572,864
static const size_t F_STATS = 47579136;   // 48
static const size_t F_TOTAL = 47579184;   // floats (~190.3 MB)

__device__ __forceinline__ float wred64(float v) {
#pragma unroll
  for (int m = 32; m; m >>= 1) v += __shfl_xor(v, m, 64);
  return v;
}

__device__ __forceinline__ float silu(float v) {
  return v / (1.f + __expf(-v));
}

__device__ __forceinline__ int map_pos(int k, int l) {
  // k0: hw order, k1: wh order, k2: hw reversed, k3: wh reversed
  if (k == 0) return l;
  if (k == 1) return ((l & 63) << 6) | (l >> 6);
  if (k == 2) return 4095 - l;
  int lp = 4095 - l;
  return ((lp & 63) << 6) | (lp >> 6);
}

// per-sample mean/rstd over n contiguous floats (f64 accumulate)
__global__ __launch_bounds__(512) void stats_kernel(const float* __restrict__ in, int n,
                                                    float* __restrict__ mean_out,
                                                    float* __restrict__ rstd_out) {
  int s = blockIdx.x;
  const float4* p = (const float4*)(in + (size_t)s * n);
  int n4 = n >> 2;
  double dsum = 0.0, dsq = 0.0;
  for (int i = threadIdx.x; i < n4; i += 512) {
    float4 v = p[i];
    dsum += (double)((v.x + v.y) + (v.z + v.w));
    dsq += (double)v.x * v.x + (double)v.y * v.y + (double)v.z * v.z + (double)v.w * v.w;
  }
  __shared__ double s1[512], s2[512];
  s1[threadIdx.x] = dsum; s2[threadIdx.x] = dsq;
  __syncthreads();
  for (int off = 256; off; off >>= 1) {
    if (threadIdx.x < off) { s1[threadIdx.x] += s1[threadIdx.x + off]; s2[threadIdx.x] += s2[threadIdx.x + off]; }
    __syncthreads();
  }
  if (threadIdx.x == 0) {
    double m = s1[0] / n;
    double var = s2[0] / n - m * m;
    mean_out[s] = (float)m;
    rstd_out[s] = (float)(1.0 / sqrt(var + 1e-5));
  }
}

// x_cat[bl][ch][p]: ch<64 dz, 64..127 instance-normed img, 128..191 sigma
__global__ __launch_bounds__(256) void build_xcat_kernel(const float* __restrict__ img,
                                                         const float* __restrict__ dz,
                                                         const float* __restrict__ sg,
                                                         const float* __restrict__ stats,
                                                         float* __restrict__ xcat) {
  size_t gid = (size_t)blockIdx.x * 256 + threadIdx.x;  // 6*192*4096 total
  int p = gid & 4095;
  size_t r = gid >> 12;
  int ch = (int)(r % NC3);
  int bl = (int)(r / NC3);
  int b = bl / 3;  // LEN=3
  float v;
  if (ch < 64) {
    v = dz[((size_t)b * NC + ch) * NHW + p];
  } else if (ch < 128) {
    float m = stats[bl], rs = stats[8 + bl];
    v = (img[((size_t)bl * NC + (ch - 64)) * NHW + p] - m) * rs;
  } else {
    v = sg[((size_t)b * NC + (ch - 128)) * NHW + p];
  }
  xcat[gid] = v;
}

// out = silu((in - mean)*rstd*g[ch] + b[ch]), NCHW flat
template <int CCH>
__global__ __launch_bounds__(256) void gn_silu_kernel(const float* __restrict__ in,
                                                      const float* __restrict__ g,
                                                      const float* __restrict__ b,
                                                      const float* __restrict__ stats,
                                                      float* __restrict__ out) {
  size_t gid = (size_t)blockIdx.x * 256 + threadIdx.x;
  size_t r = gid >> 12;
  int ch = (int)(r % CCH);
  int bl = (int)(r / CCH);
  float m = stats[bl], rs = stats[8 + bl];
  float v = (in[gid] - m) * rs * g[ch] + b[ch];
  out[gid] = silu(v);
}

// 3x3 SAME conv, Cin->64, NCHW. grid = NBL*64 (one block per (bl, h) row).
__global__ __launch_bounds__(256) void conv3x3_kernel(const float* __restrict__ in,
                                                      const float* __restrict__ wgt,
                                                      const float* __restrict__ bias,
                                                      float* __restrict__ out, int Cin) {
  int bi = blockIdx.x;
  int bl = bi >> 6, h = bi & 63;
  const int t = threadIdx.x;
  const int oc = t & 63, w0 = (t >> 6) << 4;
  __shared__ float lds[3][64][66];
  float acc[16];
#pragma unroll
  for (int i = 0; i < 16; ++i) acc[i] = 0.f;
  const int nchunk = Cin >> 6;
  for (int cc = 0; cc < nchunk; ++cc) {
    __syncthreads();
    for (int idx = t; idx < 3 * 64 * 64; idx += 256) {
      int r = idx >> 12;
      int rem = idx & 4095;
      int ch = rem >> 6, w = rem & 63;
      int hh = h + r - 1;
      float v = 0.f;
      if (hh >= 0 && hh < 64)
        v = in[(((size_t)bl * Cin + (cc << 6) + ch) << 12) + (hh << 6) + w];
      lds[r][ch][w + 1] = v;
    }
    if (t < 192) { int r = t / 64, ch = t % 64; lds[r][ch][0] = 0.f; lds[r][ch][65] = 0.f; }
    __syncthreads();
    for (int ch = 0; ch < 64; ++ch) {
      const float* wp = wgt + ((size_t)oc * Cin + (cc << 6) + ch) * 9;
      float wv[9];
#pragma unroll
      for (int j = 0; j < 9; ++j) wv[j] = wp[j];
#pragma unroll
      for (int r = 0; r < 3; ++r) {
        float xv[18];
#pragma unroll
        for (int j = 0; j < 18; ++j) xv[j] = lds[r][ch][w0 + j];
#pragma unroll
        for (int i = 0; i < 16; ++i)
          acc[i] += wv[r * 3 + 0] * xv[i] + wv[r * 3 + 1] * xv[i + 1] + wv[r * 3 + 2] * xv[i + 2];
      }
    }
  }
  float bv = bias[oc];
  size_t ob = (((size_t)bl * 64 + oc) << 12) + (h << 6) + w0;
#pragma unroll
  for (int i = 0; i < 16; ++i) out[ob + i] = acc[i] + bv;
}

// x_res[bl][p][oc] = h2[bl][oc][p] + 1x1skip(xcat)[oc] + skb[oc]   (NHWC out)
__global__ __launch_bounds__(256) void skip_kernel(const float* __restrict__ xcat,
                                                   const float* __restrict__ h2,
                                                   const float* __restrict__ skw,
                                                   const float* __restrict__ skb,
                                                   float* __restrict__ xres) {
  int bi = blockIdx.x;
  int bl = bi >> 6, h = bi & 63;
  int t = threadIdx.x;
  int oc = t & 63, w0 = (t >> 6) << 4;
  __shared__ float lds[64][64];
  float acc[16];
#pragma unroll
  for (int i = 0; i < 16; ++i) acc[i] = 0.f;
  for (int cc = 0; cc < 3; ++cc) {
    __syncthreads();
    for (int idx = t; idx < 4096; idx += 256) {
      int ch = idx >> 6, w = idx & 63;
      lds[ch][w] = xcat[(((size_t)bl * NC3 + cc * 64 + ch) << 12) + (h << 6) + w];
    }
    __syncthreads();
    for (int ch = 0; ch < 64; ++ch) {
      float wv = skw[oc * NC3 + cc * 64 + ch];
#pragma unroll
      for (int i = 0; i < 16; ++i) acc[i] += wv * lds[ch][w0 + i];
    }
  }
  float bv = skb[oc];
  int p0 = (h << 6) + w0;
#pragma unroll
  for (int i = 0; i < 16; ++i) {
    float hv = h2[(((size_t)bl * 64 + oc) << 12) + p0 + i];
    xres[((size_t)bl * NHW + p0 + i) * 64 + oc] = acc[i] + bv + hv;
  }
}

// per position: LN(ln1) then 64->256 proj; xx part -> xxin (NHWC [pi][128]), z part -> z
__global__ __launch_bounds__(256) void inproj_kernel(const float* __restrict__ xres,
                                                     const float* __restrict__ g,
                                                     const float* __restrict__ b,
                                                     const float* __restrict__ w,
                                                     float* __restrict__ xxin,
                                                     float* __restrict__ z) {
  int wv = threadIdx.x >> 6, lane = threadIdx.x & 63;
  size_t pi = (size_t)blockIdx.x * 4 + wv;  // [0, 6*4096)
  float x = xres[pi * 64 + lane];
  float s = wred64(x);
  float s2 = wred64(x * x);
  float m = s * (1.f / 64), var = s2 * (1.f / 64) - m * m;
  float rstd = rsqrtf(var + 1e-5f);
  float xln = (x - m) * rstd * g[lane] + b[lane];
  __shared__ float xb[4][64];
  xb[wv][lane] = xln;
  __syncthreads();
  float acc[4] = {0.f, 0.f, 0.f, 0.f};
  for (int c = 0; c < 64; ++c) {
    float xv = xb[wv][c];
#pragma unroll
    for (int q = 0; q < 4; ++q) acc[q] += w[(lane + (q << 6)) * 64 + c] * xv;
  }
  xxin[(pi << 7) + lane] = acc[0];
  xxin[(pi << 7) + 64 + lane] = acc[1];
  z[(pi << 7) + lane] = acc[2];
  z[(pi << 7) + 64 + lane] = acc[3];
}

// depthwise 3x3 SAME + bias + silu on NHWC [bl][p][128]
__global__ __launch_bounds__(256) void dwconv_kernel(const float* __restrict__ xx,
                                                     const float* __restrict__ w,
                                                     const float* __restrict__ b,
                                                     float* __restrict__ out) {
  size_t gid = (size_t)blockIdx.x * 256 + threadIdx.x;  // 6*4096*128
  int d = gid & 127;
  size_t pi = gid >> 7;
  int p = (int)(pi & 4095);
  int bl = (int)(pi >> 12);
  int h = p >> 6, wq = p & 63;
  float acc = b[d];
  const float* wr = w + d * 9;
#pragma unroll
  for (int dy = -1; dy <= 1; ++dy) {
    int hh = h + dy;
    if (hh < 0 || hh >= 64) continue;
#pragma unroll
    for (int dx = -1; dx <= 1; ++dx) {
      int ww = wq + dx;
      if (ww < 0 || ww >= 64) continue;
      acc += wr[(dy + 1) * 3 + (dx + 1)] * xx[(((size_t)bl << 12) + (hh << 6) + ww) * 128 + d];
    }
  }
  out[pi * 128 + d] = silu(acc);
}

// x_dbl[bk][c][l] = sum_d xpw[k][c][d] * xs[bk][d][l]  (xs gathered via map_pos)
__global__ __launch_bounds__(256) void xdbl_kernel(const float* __restrict__ xxc,
                                                   const float* __restrict__ xpw,
                                                   float* __restrict__ xdbl) {
  int bi = blockIdx.x;               // NBL*NK*64
  int lt = bi & 63;
  int k = (bi >> 6) & 3;
  int bl = bi >> 8;
  int lbase = lt << 6;
  __shared__ float lds[64][129];
  int t = threadIdx.x;
  for (int idx = t; idx < 64 * 128; idx += 256) {
    int i = idx >> 7, d = idx & 127;
    int pos = map_pos(k, lbase + i);
    lds[i][d] = xxc[((size_t)bl * NHW + pos) * 128 + d];
  }
  __syncthreads();
  for (int oi = t; oi < 36 * 64; oi += 256) {
    int c = oi >> 6, l = oi & 63;
    const float* wrow = xpw + (k * 36 + c) * 128;
    float acc = 0.f;
    for (int d = 0; d < 128; ++d) acc += wrow[d] * lds[l][d];
    xdbl[(((size_t)(bl * 4 + k)) * 36 + c) * (size_t)NL + lbase + l] = acc;
  }
}

// delta[bk][d][l] = softplus(sum_r dtw[k][d][r]*xdbl[bk][r][l] + dtb[k][d])
__global__ __launch_bounds__(256) void delta_kernel(const float* __restrict__ xdbl,
                                                    const float* __restrict__ dtw,
                                                    const float* __restrict__ dtb,
                                                    float* __restrict__ delta) {
  size_t gid = (size_t)blockIdx.x * 256 + threadIdx.x;  // 6*4*128*4096
  int l = gid & 4095;
  size_t r = gid >> 12;
  int d = (int)(r & 127);
  size_t bk = r >> 7;
  int k = (int)(bk & 3);
  const float* xb = xdbl + bk * 36 * (size_t)NL + l;
  float acc = dtb[(k << 7) + d];
  const float* wr = dtw + ((k << 7) + d) * 4;
#pragma unroll
  for (int rr = 0; rr < 4; ++rr) acc += wr[rr] * xb[(size_t)rr * NL];
  float sp = (acc > 20.f) ? acc : log1pf(__expf(acc));
  delta[gid] = sp;
}

// selective scan. grid NBL*NK*8, block 256 = 16 d x 16 n.
__global__ __launch_bounds__(256) void scan_kernel(const float* __restrict__ delta,
                                                   const float* __restrict__ xdbl,
                                                   const float* __restrict__ xxc,
                                                   const float* __restrict__ Alog,
                                                   float* __restrict__ ys) {
  int bi = blockIdx.x;
  int dchunk = bi & 7;
  int k = (bi >> 3) & 3;
  int bl = bi >> 5;
  int t = threadIdx.x;
  int dl = t >> 4, n = t & 15;
  int d = (dchunk << 4) + dl;
  float A = -__expf(Alog[((k << 7) + d) * 16 + n]);
  size_t bk = (size_t)(bl * 4 + k);
  const float* dB = delta + ((bk << 7) + d) * (size_t)NL;
  const float* BB = xdbl + (bk * 36 + 4 + n) * (size_t)NL;
  const float* CB = xdbl + (bk * 36 + 20 + n) * (size_t)NL;
  const float* uB = xxc + (((size_t)bl) << 12) * 128 + d;
  float* yB = ys + (bk << 12) * 128 + d;
  float h = 0.f;
  for (int l = 0; l < NL; ++l) {
    int pos = map_pos(k, l);
    float dt = dB[l];
    float u = uB[(size_t)pos << 7];
    float Bv = BB[l], Cv = CB[l];
    h = __expf(dt * A) * h + dt * Bv * u;
    float yc = h * Cv;
    yc += __shfl_xor(yc, 1, 64);
    yc += __shfl_xor(yc, 2, 64);
    yc += __shfl_xor(yc, 4, 64);
    yc += __shfl_xor(yc, 8, 64);
    if (n == 0) yB[(size_t)l << 7] = yc;
  }
}

// ycomb[bl][p][d] = sum of 4 direction outputs (mapped) + xxc * sum_k Ds
__global__ __launch_bounds__(256) void combine_kernel(const float* __restrict__ ys,
                                                      const float* __restrict__ xxc,
                                                      const float* __restrict__ Ds,
                                                      float* __restrict__ ycomb) {
  size_t gid = (size_t)blockIdx.x * 256 + threadIdx.x;  // 6*4096*128
  int d = gid & 127;
  size_t pi = gid >> 7;
  int p = (int)(pi & 4095);
  int bl = (int)(pi >> 12);
  int h = p >> 6, w = p & 63;
  int l1 = (w << 6) | h;
  size_t base = ((size_t)bl * 4) << 12;
  float v = ys[((base + p) << 7) + d]
          + ys[((base + 4096 + l1) << 7) + d]
          + ys[((base + 2 * 4096 + (4095 - p)) << 7) + d]
          + ys[((base + 3 * 4096 + (4095 - l1)) << 7) + d];
  float ds = Ds[d] + Ds[128 + d] + Ds[256 + d] + Ds[384 + d];
  v += xxc[(pi << 7) + d] * ds;
  ycomb[(pi << 7) + d] = v;
}

// out_norm LN(128) -> *silu(z) -> out_proj 128->64 -> + x_res
__global__ __launch_bounds__(256) void outproj_kernel(const float* __restrict__ ycomb,
                                                      const float* __restrict__ z,
                                                      const float* __restrict__ ong,
                                                      const float* __restrict__ onb,
                                                      const float* __restrict__ opw,
                                                      const float* __restrict__ xres,
                                                      float* __restrict__ x1) {
  int wv = threadIdx.x >> 6, lane = threadIdx.x & 63;
  size_t pi = (size_t)blockIdx.x * 4 + wv;
  float y0 = ycomb[(pi << 7) + lane], y1 = ycomb[(pi << 7) + 64 + lane];
  float s = wred64(y0 + y1);
  float s2 = wred64(y0 * y0 + y1 * y1);
  float m = s * (1.f / 128), var = s2 * (1.f / 128) - m * m;
  float rstd = rsqrtf(var + 1e-5f);
  float z0 = z[(pi << 7) + lane], z1 = z[(pi << 7) + 64 + lane];
  float g0 = ((y0 - m) * rstd * ong[lane] + onb[lane]) * silu(z0);
  float g1 = ((y1 - m) * rstd * ong[64 + lane] + onb[64 + lane]) * silu(z1);
  __shared__ float gb[4][128];
  gb[wv][lane] = g0;
  gb[wv][64 + lane] = g1;
  __syncthreads();
  float acc = 0.f;
  const float* wrow = opw + lane * 128;
  for (int i = 0; i < 128; ++i) acc += wrow[i] * gb[wv][i];
  x1[pi * 64 + lane] = xres[pi * 64 + lane] + acc;
}

// ln2 -> fc1 -> gelu(tanh) -> fc2 -> residual; NHWC
__global__ __launch_bounds__(256) void mlp_kernel(const float* __restrict__ x1,
                                                  const float* __restrict__ g2,
                                                  const float* __restrict__ b2,
                                                  const float* __restrict__ w1,
                                                  const float* __restrict__ bb1,
                                                  const float* __restrict__ w2,
                                                  const float* __restrict__ bb2,
                                                  float* __restrict__ x2) {
  int wv = threadIdx.x >> 6, lane = threadIdx.x & 63;
  size_t pi = (size_t)blockIdx.x * 4 + wv;
  float xv = x1[pi * 64 + lane];
  float s = wred64(xv), s2 = wred64(xv * xv);
  float m = s * (1.f / 64), var = s2 * (1.f / 64) - m * m;
  float rstd = rsqrtf(var + 1e-5f);
  float xm = (xv - m) * rstd * g2[lane] + b2[lane];
  __shared__ float xb[4][64], tb[4][64];
  xb[wv][lane] = xm;
  __syncthreads();
  float acc = bb1[lane];
  const float* wr = w1 + lane * 64;
  for (int i = 0; i < 64; ++i) acc += wr[i] * xb[wv][i];
  float u = acc;
  float tt = tanhf(0.7978845608028654f * (u + 0.044715f * u * u * u));
  float t1 = 0.5f * u * (1.f + tt);
  tb[wv][lane] = t1;
  __syncthreads();
  float acc2 = bb2[lane];
  const float* wr2 = w2 + lane * 64;
  for (int i = 0; i < 64; ++i) acc2 += wr2[i] * tb[wv][i];
  x2[pi * 64 + lane] = xv + acc2;
}

// NHWC (bl,p,c) -> NCHW (bl,c,p) tiled transpose into d_out
__global__ __launch_bounds__(256) void transpose_out_kernel(const float* __restrict__ x2,
                                                            float* __restrict__ out) {
  int bi = blockIdx.x;  // NBL * 2 * 128
  int pt = bi & 127;
  int ct = (bi >> 7) & 1;
  int bl = bi >> 8;
  __shared__ float lds[32][33];
  int t = threadIdx.x;
  int j = t & 31, i0 = t >> 5;
  int p0 = pt << 5, c0 = ct << 5;
#pragma unroll
  for (int q = 0; q < 4; ++q) {
    int i = i0 + (q << 3);
    lds[i][j] = x2[((size_t)bl * NHW + p0 + i) * 64 + c0 + j];
  }
  __syncthreads();
#pragma unroll
  for (int q = 0; q < 4; ++q) {
    int i = i0 + (q << 3);
    out[((size_t)bl * 64 + c0 + i) * (size_t)NHW + p0 + j] = lds[j][i];
  }
}

extern "C" void kernel_launch(void* const* d_in, const int* in_sizes, int n_in,
                              void* d_out, int out_size, void* d_ws, size_t ws_size,
                              hipStream_t stream) {
  const float* img  = (const float*)d_in[0];
  const float* dz   = (const float*)d_in[1];
  const float* sg   = (const float*)d_in[2];
  const float* gn1g = (const float*)d_in[3];
  const float* gn1b = (const float*)d_in[4];
  const float* c1w  = (const float*)d_in[5];
  const float* c1b  = (const float*)d_in[6];
  const float* gn2g = (const float*)d_in[7];
  const float* gn2b = (const float*)d_in[8];
  const float* c2w  = (const float*)d_in[9];
  const float* c2b  = (const float*)d_in[10];
  const float* skw  = (const float*)d_in[11];
  const float* skb  = (const float*)d_in[12];
  const float* ln1g = (const float*)d_in[13];
  const float* ln1b = (const float*)d_in[14];
  const float* ln2g = (const float*)d_in[15];
  const float* ln2b = (const float*)d_in[16];
  const float* ipw  = (const float*)d_in[17];
  const float* dww  = (const float*)d_in[18];
  const float* dwb  = (const float*)d_in[19];
  const float* xpw  = (const float*)d_in[20];
  const float* dtw  = (const float*)d_in[21];
  const float* dtb  = (const float*)d_in[22];
  const float* Alog = (const float*)d_in[23];
  const float* Dsp  = (const float*)d_in[24];
  const float* ong  = (const float*)d_in[25];
  const float* onb  = (const float*)d_in[26];
  const float* opw  = (const float*)d_in[27];
  const float* f1w  = (const float*)d_in[28];
  const float* f1b  = (const float*)d_in[29];
  const float* f2w  = (const float*)d_in[30];
  const float* f2b  = (const float*)d_in[31];

  float* out = (float*)d_out;
  float* ws = (float*)d_ws;
  if (ws_size < F_TOTAL * sizeof(float)) return;

  float* xcat  = ws + F_XCAT;
  float* act1  = ws + F_ACT1;
  float* h1    = ws + F_H1;
  float* act2  = ws + F_ACT2;
  float* h2    = ws + F_H2;
  float* deltb = ws + F_DELTA;
  float* xres  = ws + F_XRES;
  float* xxin  = ws + F_XXIN;
  float* zbuf  = ws + F_Z;
  float* xxc   = ws + F_XXC;
  float* xdbl  = ws + F_XDBL;
  float* ysb   = ws + F_YS;
  float* ycomb = ws + F_YCOMB;
  float* x1    = ws + F_X1;
  float* x2    = ws + F_X2;
  float* stats = ws + F_STATS;

  // stage 0: instance-norm stats over image per (b,l)
  stats_kernel<<<NBL, 512, 0, stream>>>(img, NC * NHW, stats + 0, stats + 8);
  build_xcat_kernel<<<18432, 256, 0, stream>>>(img, dz, sg, stats, xcat);
  // gn1 + silu
  stats_kernel<<<NBL, 512, 0, stream>>>(xcat, NC3 * NHW, stats + 16, stats + 24);
  gn_silu_kernel<NC3><<<18432, 256, 0, stream>>>(xcat, gn1g, gn1b, stats + 16, act1);
  conv3x3_kernel<<<NBL * 64, 256, 0, stream>>>(act1, c1w, c1b, h1, NC3);
  // gn2 + silu
  stats_kernel<<<NBL, 512, 0, stream>>>(h1, NC * NHW, stats + 32, stats + 40);
  gn_silu_kernel<NC><<<6144, 256, 0, stream>>>(h1, gn2g, gn2b, stats + 32, act2);
  conv3x3_kernel<<<NBL * 64, 256, 0, stream>>>(act2, c2w, c2b, h2, NC);
  // skip 1x1 + residual + NHWC transpose
  skip_kernel<<<NBL * 64, 256, 0, stream>>>(xcat, h2, skw, skb, xres);
  // SS2D
  inproj_kernel<<<6144, 256, 0, stream>>>(xres, ln1g, ln1b, ipw, xxin, zbuf);
  dwconv_kernel<<<12288, 256, 0, stream>>>(xxin, dww, dwb, xxc);
  xdbl_kernel<<<NBL * NK * 64, 256, 0, stream>>>(xxc, xpw, xdbl);
  delta_kernel<<<49152, 256, 0, stream>>>(xdbl, dtw, dtb, deltb);
  scan_kernel<<<NBL * NK * 8, 256, 0, stream>>>(deltb, xdbl, xxc, Alog, ysb);
  combine_kernel<<<12288, 256, 0, stream>>>(ysb, xxc, Dsp, ycomb);
  outproj_kernel<<<6144, 256, 0, stream>>>(ycomb, zbuf, ong, onb, opw, xres, x1);
  // MLP + residual
  mlp_kernel<<<6144, 256, 0, stream>>>(x1, ln2g, ln2b, f1w, f1b, f2w, f2b, x2);
  // final transpose to NCHW output
  transpose_out_kernel<<<NBL * 256, 256, 0, stream>>>(x2, out);
}

// Round 2
// 2143.014 us; speedup vs baseline: 1.4013x; 1.4013x over previous
//
#include <hip/hip_runtime.h>
#include <hip/hip_bf16.h>

// Problem constants
#define NBL 6      // B*LEN
#define NC 64
#define NC3 192
#define NHW 4096   // 64*64
#define NDI 128
#define NNS 16
#define NDR 4
#define NK 4
#define NL 4096
#define NCH 64     // scan chunks
#define CLEN 64    // chunk length
#define NSTATE 49152  // 24 bk * 128 d * 16 n

// workspace offsets in floats
static const size_t F_XCAT  = 0;          // 6*192*4096 = 4,718,592
static const size_t F_ACT1  = 4718592;    // 4,718,592
static const size_t F_H1    = 9437184;    // 1,572,864
static const size_t F_ACT2  = 11010048;   // 1,572,864
static const size_t F_H2    = 12582912;   // 1,572,864
static const size_t F_DELTA = 0;          // 12,582,912 — aliases XCAT..ACT2 (dead by then)
static const size_t F_XRES  = 14155776;   // 1,572,864
static const size_t F_XXIN  = 15728640;   // 3,145,728  (dead after dwconv -> chunkP)
static const size_t F_Z     = 18874368;   // 3,145,728
static const size_t F_XXC   = 22020096;   // 3,145,728
static const size_t F_XDBL  = 25165824;   // 6*4*36*4096 = 3,538,944
static const size_t F_YS    = 28704768;   // 12,582,912
static const size_t F_YCOMB = 41287680;   // 3,145,728  (written after scan -> chunkH during scan)
static const size_t F_X1    = 44433408;   // 1,572,864  (X1+X2 = 3,145,728 -> chunkHS during scan)
static const size_t F_X2    = 46006272;   // 1,572,864
static const size_t F_STATS = 47579136;   // 48
static const size_t F_TOTAL = 47579184;   // floats (~190.3 MB)

__device__ __forceinline__ float wred64(float v) {
#pragma unroll
  for (int m = 32; m; m >>= 1) v += __shfl_xor(v, m, 64);
  return v;
}

__device__ __forceinline__ float silu(float v) {
  return v / (1.f + __expf(-v));
}

__device__ __forceinline__ int map_pos(int k, int l) {
  // k0: hw order, k1: wh order, k2: hw reversed, k3: wh reversed
  if (k == 0) return l;
  if (k == 1) return ((l & 63) << 6) | (l >> 6);
  if (k == 2) return 4095 - l;
  int lp = 4095 - l;
  return ((lp & 63) << 6) | (lp >> 6);
}

// per-sample mean/rstd over n contiguous floats (f64 accumulate)
__global__ __launch_bounds__(512) void stats_kernel(const float* __restrict__ in, int n,
                                                    float* __restrict__ mean_out,
                                                    float* __restrict__ rstd_out) {
  int s = blockIdx.x;
  const float4* p = (const float4*)(in + (size_t)s * n);
  int n4 = n >> 2;
  double dsum = 0.0, dsq = 0.0;
  for (int i = threadIdx.x; i < n4; i += 512) {
    float4 v = p[i];
    dsum += (double)((v.x + v.y) + (v.z + v.w));
    dsq += (double)v.x * v.x + (double)v.y * v.y + (double)v.z * v.z + (double)v.w * v.w;
  }
  __shared__ double s1[512], s2[512];
  s1[threadIdx.x] = dsum; s2[threadIdx.x] = dsq;
  __syncthreads();
  for (int off = 256; off; off >>= 1) {
    if (threadIdx.x < off) { s1[threadIdx.x] += s1[threadIdx.x + off]; s2[threadIdx.x] += s2[threadIdx.x + off]; }
    __syncthreads();
  }
  if (threadIdx.x == 0) {
    double m = s1[0] / n;
    double var = s2[0] / n - m * m;
    mean_out[s] = (float)m;
    rstd_out[s] = (float)(1.0 / sqrt(var + 1e-5));
  }
}

// x_cat[bl][ch][p]: ch<64 dz, 64..127 instance-normed img, 128..191 sigma
__global__ __launch_bounds__(256) void build_xcat_kernel(const float* __restrict__ img,
                                                         const float* __restrict__ dz,
                                                         const float* __restrict__ sg,
                                                         const float* __restrict__ stats,
                                                         float* __restrict__ xcat) {
  size_t gid = (size_t)blockIdx.x * 256 + threadIdx.x;  // 6*192*4096 total
  int p = gid & 4095;
  size_t r = gid >> 12;
  int ch = (int)(r % NC3);
  int bl = (int)(r / NC3);
  int b = bl / 3;  // LEN=3
  float v;
  if (ch < 64) {
    v = dz[((size_t)b * NC + ch) * NHW + p];
  } else if (ch < 128) {
    float m = stats[bl], rs = stats[8 + bl];
    v = (img[((size_t)bl * NC + (ch - 64)) * NHW + p] - m) * rs;
  } else {
    v = sg[((size_t)b * NC + (ch - 128)) * NHW + p];
  }
  xcat[gid] = v;
}

// out = silu((in - mean)*rstd*g[ch] + b[ch]), NCHW flat
template <int CCH>
__global__ __launch_bounds__(256) void gn_silu_kernel(const float* __restrict__ in,
                                                      const float* __restrict__ g,
                                                      const float* __restrict__ b,
                                                      const float* __restrict__ stats,
                                                      float* __restrict__ out) {
  size_t gid = (size_t)blockIdx.x * 256 + threadIdx.x;
  size_t r = gid >> 12;
  int ch = (int)(r % CCH);
  int bl = (int)(r / CCH);
  float m = stats[bl], rs = stats[8 + bl];
  float v = (in[gid] - m) * rs * g[ch] + b[ch];
  out[gid] = silu(v);
}

// 3x3 SAME conv, Cin->64, NCHW. grid = NBL*64 (one block per (bl, h) row).
__global__ __launch_bounds__(256) void conv3x3_kernel(const float* __restrict__ in,
                                                      const float* __restrict__ wgt,
                                                      const float* __restrict__ bias,
                                                      float* __restrict__ out, int Cin) {
  int bi = blockIdx.x;
  int bl = bi >> 6, h = bi & 63;
  const int t = threadIdx.x;
  const int oc = t & 63, w0 = (t >> 6) << 4;
  __shared__ float lds[3][64][66];
  float acc[16];
#pragma unroll
  for (int i = 0; i < 16; ++i) acc[i] = 0.f;
  const int nchunk = Cin >> 6;
  for (int cc = 0; cc < nchunk; ++cc) {
    __syncthreads();
    for (int idx = t; idx < 3 * 64 * 64; idx += 256) {
      int r = idx >> 12;
      int rem = idx & 4095;
      int ch = rem >> 6, w = rem & 63;
      int hh = h + r - 1;
      float v = 0.f;
      if (hh >= 0 && hh < 64)
        v = in[(((size_t)bl * Cin + (cc << 6) + ch) << 12) + (hh << 6) + w];
      lds[r][ch][w + 1] = v;
    }
    if (t < 192) { int r = t / 64, ch = t % 64; lds[r][ch][0] = 0.f; lds[r][ch][65] = 0.f; }
    __syncthreads();
    for (int ch = 0; ch < 64; ++ch) {
      const float* wp = wgt + ((size_t)oc * Cin + (cc << 6) + ch) * 9;
      float wv[9];
#pragma unroll
      for (int j = 0; j < 9; ++j) wv[j] = wp[j];
#pragma unroll
      for (int r = 0; r < 3; ++r) {
        float xv[18];
#pragma unroll
        for (int j = 0; j < 18; ++j) xv[j] = lds[r][ch][w0 + j];
#pragma unroll
        for (int i = 0; i < 16; ++i)
          acc[i] += wv[r * 3 + 0] * xv[i] + wv[r * 3 + 1] * xv[i + 1] + wv[r * 3 + 2] * xv[i + 2];
      }
    }
  }
  float bv = bias[oc];
  size_t ob = (((size_t)bl * 64 + oc) << 12) + (h << 6) + w0;
#pragma unroll
  for (int i = 0; i < 16; ++i) out[ob + i] = acc[i] + bv;
}

// x_res[bl][p][oc] = h2[bl][oc][p] + 1x1skip(xcat)[oc] + skb[oc]   (NHWC out)
__global__ __launch_bounds__(256) void skip_kernel(const float* __restrict__ xcat,
                                                   const float* __restrict__ h2,
                                                   const float* __restrict__ skw,
                                                   const float* __restrict__ skb,
                                                   float* __restrict__ xres) {
  int bi = blockIdx.x;
  int bl = bi >> 6, h = bi & 63;
  int t = threadIdx.x;
  int oc = t & 63, w0 = (t >> 6) << 4;
  __shared__ float lds[64][64];
  float acc[16];
#pragma unroll
  for (int i = 0; i < 16; ++i) acc[i] = 0.f;
  for (int cc = 0; cc < 3; ++cc) {
    __syncthreads();
    for (int idx = t; idx < 4096; idx += 256) {
      int ch = idx >> 6, w = idx & 63;
      lds[ch][w] = xcat[(((size_t)bl * NC3 + cc * 64 + ch) << 12) + (h << 6) + w];
    }
    __syncthreads();
    for (int ch = 0; ch < 64; ++ch) {
      float wv = skw[oc * NC3 + cc * 64 + ch];
#pragma unroll
      for (int i = 0; i < 16; ++i) acc[i] += wv * lds[ch][w0 + i];
    }
  }
  float bv = skb[oc];
  int p0 = (h << 6) + w0;
#pragma unroll
  for (int i = 0; i < 16; ++i) {
    float hv = h2[(((size_t)bl * 64 + oc) << 12) + p0 + i];
    xres[((size_t)bl * NHW + p0 + i) * 64 + oc] = acc[i] + bv + hv;
  }
}

// per position: LN(ln1) then 64->256 proj; xx part -> xxin (NHWC [pi][128]), z part -> z
__global__ __launch_bounds__(256) void inproj_kernel(const float* __restrict__ xres,
                                                     const float* __restrict__ g,
                                                     const float* __restrict__ b,
                                                     const float* __restrict__ w,
                                                     float* __restrict__ xxin,
                                                     float* __restrict__ z) {
  int wv = threadIdx.x >> 6, lane = threadIdx.x & 63;
  size_t pi = (size_t)blockIdx.x * 4 + wv;  // [0, 6*4096)
  float x = xres[pi * 64 + lane];
  float s = wred64(x);
  float s2 = wred64(x * x);
  float m = s * (1.f / 64), var = s2 * (1.f / 64) - m * m;
  float rstd = rsqrtf(var + 1e-5f);
  float xln = (x - m) * rstd * g[lane] + b[lane];
  __shared__ float xb[4][64];
  xb[wv][lane] = xln;
  __syncthreads();
  float acc[4] = {0.f, 0.f, 0.f, 0.f};
  for (int c = 0; c < 64; ++c) {
    float xv = xb[wv][c];
#pragma unroll
    for (int q = 0; q < 4; ++q) acc[q] += w[(lane + (q << 6)) * 64 + c] * xv;
  }
  xxin[(pi << 7) + lane] = acc[0];
  xxin[(pi << 7) + 64 + lane] = acc[1];
  z[(pi << 7) + lane] = acc[2];
  z[(pi << 7) + 64 + lane] = acc[3];
}

// depthwise 3x3 SAME + bias + silu on NHWC [bl][p][128]
__global__ __launch_bounds__(256) void dwconv_kernel(const float* __restrict__ xx,
                                                     const float* __restrict__ w,
                                                     const float* __restrict__ b,
                                                     float* __restrict__ out) {
  size_t gid = (size_t)blockIdx.x * 256 + threadIdx.x;  // 6*4096*128
  int d = gid & 127;
  size_t pi = gid >> 7;
  int p = (int)(pi & 4095);
  int bl = (int)(pi >> 12);
  int h = p >> 6, wq = p & 63;
  float acc = b[d];
  const float* wr = w + d * 9;
#pragma unroll
  for (int dy = -1; dy <= 1; ++dy) {
    int hh = h + dy;
    if (hh < 0 || hh >= 64) continue;
#pragma unroll
    for (int dx = -1; dx <= 1; ++dx) {
      int ww = wq + dx;
      if (ww < 0 || ww >= 64) continue;
      acc += wr[(dy + 1) * 3 + (dx + 1)] * xx[(((size_t)bl << 12) + (hh << 6) + ww) * 128 + d];
    }
  }
  out[pi * 128 + d] = silu(acc);
}

// x_dbl[bk][c][l] = sum_d xpw[k][c][d] * xs[bk][d][l]  (xs gathered via map_pos)
__global__ __launch_bounds__(256) void xdbl_kernel(const float* __restrict__ xxc,
                                                   const float* __restrict__ xpw,
                                                   float* __restrict__ xdbl) {
  int bi = blockIdx.x;               // NBL*NK*64
  int lt = bi & 63;
  int k = (bi >> 6) & 3;
  int bl = bi >> 8;
  int lbase = lt << 6;
  __shared__ float lds[64][129];
  int t = threadIdx.x;
  for (int idx = t; idx < 64 * 128; idx += 256) {
    int i = idx >> 7, d = idx & 127;
    int pos = map_pos(k, lbase + i);
    lds[i][d] = xxc[((size_t)bl * NHW + pos) * 128 + d];
  }
  __syncthreads();
  for (int oi = t; oi < 36 * 64; oi += 256) {
    int c = oi >> 6, l = oi & 63;
    const float* wrow = xpw + (k * 36 + c) * 128;
    float acc = 0.f;
    for (int d = 0; d < 128; ++d) acc += wrow[d] * lds[l][d];
    xdbl[(((size_t)(bl * 4 + k)) * 36 + c) * (size_t)NL + lbase + l] = acc;
  }
}

// delta[bk][d][l] = softplus(sum_r dtw[k][d][r]*xdbl[bk][r][l] + dtb[k][d])
__global__ __launch_bounds__(256) void delta_kernel(const float* __restrict__ xdbl,
                                                    const float* __restrict__ dtw,
                                                    const float* __restrict__ dtb,
                                                    float* __restrict__ delta) {
  size_t gid = (size_t)blockIdx.x * 256 + threadIdx.x;  // 6*4*128*4096
  int l = gid & 4095;
  size_t r = gid >> 12;
  int d = (int)(r & 127);
  size_t bk = r >> 7;
  int k = (int)(bk & 3);
  const float* xb = xdbl + bk * 36 * (size_t)NL + l;
  float acc = dtb[(k << 7) + d];
  const float* wr = dtw + ((k << 7) + d) * 4;
#pragma unroll
  for (int rr = 0; rr < 4; ++rr) acc += wr[rr] * xb[(size_t)rr * NL];
  float sp = (acc > 20.f) ? acc : log1pf(__expf(acc));
  delta[gid] = sp;
}

// ---- chunked selective scan ----
// Pass 1: per-chunk local scan from h=0; store P = exp(A*sum_dt) and local end state.
// grid: bl(6) x k(4) x dchunk(8) x chunk(64) = 12288 blocks, block 256 = 16dl x 16n
__global__ __launch_bounds__(256) void scan_pass1_kernel(const float* __restrict__ delta,
                                                         const float* __restrict__ xdbl,
                                                         const float* __restrict__ xxc,
                                                         const float* __restrict__ Alog,
                                                         float* __restrict__ chunkP,
                                                         float* __restrict__ chunkH) {
  int bi = blockIdx.x;
  int chunk = bi & 63;
  int dchunk = (bi >> 6) & 7;
  int k = (bi >> 9) & 3;
  int bl = bi >> 11;
  int t = threadIdx.x;
  int dl = t >> 4, n = t & 15;
  int d = (dchunk << 4) + dl;
  float A = -__expf(Alog[((k << 7) + d) * 16 + n]);
  size_t bk = (size_t)(bl * 4 + k);
  const float* dB = delta + ((bk << 7) + d) * (size_t)NL;
  const float* BB = xdbl + (bk * 36 + 4 + n) * (size_t)NL;
  const float* uB = xxc + ((((size_t)bl) << 12) << 7) + d;
  int l0 = chunk << 6;
  float h = 0.f, sdt = 0.f;
#pragma unroll 4
  for (int li = 0; li < CLEN; ++li) {
    int l = l0 + li;
    int pos = map_pos(k, l);
    float dt = dB[l];
    float u = uB[(size_t)pos << 7];
    float Bv = BB[l];
    h = __expf(dt * A) * h + dt * Bv * u;
    sdt += dt;
  }
  size_t gs = ((bk << 7) + d) * 16 + n;              // global state index
  chunkP[(size_t)chunk * NSTATE + gs] = __expf(A * sdt);
  chunkH[(size_t)chunk * NSTATE + gs] = h;
}

// Pass 2: sequential combine over 64 chunks per state. grid 192 x 256.
__global__ __launch_bounds__(256) void scan_pass2_kernel(const float* __restrict__ chunkP,
                                                         const float* __restrict__ chunkH,
                                                         float* __restrict__ chunkHS) {
  size_t state = (size_t)blockIdx.x * 256 + threadIdx.x;  // < 49152
  float h = 0.f;
#pragma unroll 4
  for (int j = 0; j < NCH; ++j) {
    size_t idx = (size_t)j * NSTATE + state;
    chunkHS[idx] = h;
    h = chunkP[idx] * h + chunkH[idx];
  }
}

// Pass 3: re-run local scan seeded with h_start; emit y.
__global__ __launch_bounds__(256) void scan_pass3_kernel(const float* __restrict__ delta,
                                                         const float* __restrict__ xdbl,
                                                         const float* __restrict__ xxc,
                                                         const float* __restrict__ Alog,
                                                         const float* __restrict__ chunkHS,
                                                         float* __restrict__ ys) {
  int bi = blockIdx.x;
  int chunk = bi & 63;
  int dchunk = (bi >> 6) & 7;
  int k = (bi >> 9) & 3;
  int bl = bi >> 11;
  int t = threadIdx.x;
  int dl = t >> 4, n = t & 15;
  int d = (dchunk << 4) + dl;
  float A = -__expf(Alog[((k << 7) + d) * 16 + n]);
  size_t bk = (size_t)(bl * 4 + k);
  const float* dB = delta + ((bk << 7) + d) * (size_t)NL;
  const float* BB = xdbl + (bk * 36 + 4 + n) * (size_t)NL;
  const float* CB = xdbl + (bk * 36 + 20 + n) * (size_t)NL;
  const float* uB = xxc + ((((size_t)bl) << 12) << 7) + d;
  float* yB = ys + ((bk << 12) << 7) + d;
  size_t gs = ((bk << 7) + d) * 16 + n;
  float h = chunkHS[(size_t)chunk * NSTATE + gs];
  int l0 = chunk << 6;
  for (int li = 0; li < CLEN; ++li) {
    int l = l0 + li;
    int pos = map_pos(k, l);
    float dt = dB[l];
    float u = uB[(size_t)pos << 7];
    float Bv = BB[l], Cv = CB[l];
    h = __expf(dt * A) * h + dt * Bv * u;
    float yc = h * Cv;
    yc += __shfl_xor(yc, 1, 64);
    yc += __shfl_xor(yc, 2, 64);
    yc += __shfl_xor(yc, 4, 64);
    yc += __shfl_xor(yc, 8, 64);
    if (n == 0) yB[(size_t)l << 7] = yc;
  }
}

// ycomb[bl][p][d] = sum of 4 direction outputs (mapped) + xxc * sum_k Ds
__global__ __launch_bounds__(256) void combine_kernel(const float* __restrict__ ys,
                                                      const float* __restrict__ xxc,
                                                      const float* __restrict__ Ds,
                                                      float* __restrict__ ycomb) {
  size_t gid = (size_t)blockIdx.x * 256 + threadIdx.x;  // 6*4096*128
  int d = gid & 127;
  size_t pi = gid >> 7;
  int p = (int)(pi & 4095);
  int bl = (int)(pi >> 12);
  int h = p >> 6, w = p & 63;
  int l1 = (w << 6) | h;
  size_t base = ((size_t)bl * 4) << 12;
  float v = ys[((base + p) << 7) + d]
          + ys[((base + 4096 + l1) << 7) + d]
          + ys[((base + 2 * 4096 + (4095 - p)) << 7) + d]
          + ys[((base + 3 * 4096 + (4095 - l1)) << 7) + d];
  float ds = Ds[d] + Ds[128 + d] + Ds[256 + d] + Ds[384 + d];
  v += xxc[(pi << 7) + d] * ds;
  ycomb[(pi << 7) + d] = v;
}

// out_norm LN(128) -> *silu(z) -> out_proj 128->64 -> + x_res
__global__ __launch_bounds__(256) void outproj_kernel(const float* __restrict__ ycomb,
                                                      const float* __restrict__ z,
                                                      const float* __restrict__ ong,
                                                      const float* __restrict__ onb,
                                                      const float* __restrict__ opw,
                                                      const float* __restrict__ xres,
                                                      float* __restrict__ x1) {
  int wv = threadIdx.x >> 6, lane = threadIdx.x & 63;
  size_t pi = (size_t)blockIdx.x * 4 + wv;
  float y0 = ycomb[(pi << 7) + lane], y1 = ycomb[(pi << 7) + 64 + lane];
  float s = wred64(y0 + y1);
  float s2 = wred64(y0 * y0 + y1 * y1);
  float m = s * (1.f / 128), var = s2 * (1.f / 128) - m * m;
  float rstd = rsqrtf(var + 1e-5f);
  float z0 = z[(pi << 7) + lane], z1 = z[(pi << 7) + 64 + lane];
  float g0 = ((y0 - m) * rstd * ong[lane] + onb[lane]) * silu(z0);
  float g1 = ((y1 - m) * rstd * ong[64 + lane] + onb[64 + lane]) * silu(z1);
  __shared__ float gb[4][128];
  gb[wv][lane] = g0;
  gb[wv][64 + lane] = g1;
  __syncthreads();
  float acc = 0.f;
  const float* wrow = opw + lane * 128;
  for (int i = 0; i < 128; ++i) acc += wrow[i] * gb[wv][i];
  x1[pi * 64 + lane] = xres[pi * 64 + lane] + acc;
}

// ln2 -> fc1 -> gelu(tanh) -> fc2 -> residual; NHWC
__global__ __launch_bounds__(256) void mlp_kernel(const float* __restrict__ x1,
                                                  const float* __restrict__ g2,
                                                  const float* __restrict__ b2,
                                                  const float* __restrict__ w1,
                                                  const float* __restrict__ bb1,
                                                  const float* __restrict__ w2,
                                                  const float* __restrict__ bb2,
                                                  float* __restrict__ x2) {
  int wv = threadIdx.x >> 6, lane = threadIdx.x & 63;
  size_t pi = (size_t)blockIdx.x * 4 + wv;
  float xv = x1[pi * 64 + lane];
  float s = wred64(xv), s2 = wred64(xv * xv);
  float m = s * (1.f / 64), var = s2 * (1.f / 64) - m * m;
  float rstd = rsqrtf(var + 1e-5f);
  float xm = (xv - m) * rstd * g2[lane] + b2[lane];
  __shared__ float xb[4][64], tb[4][64];
  xb[wv][lane] = xm;
  __syncthreads();
  float acc = bb1[lane];
  const float* wr = w1 + lane * 64;
  for (int i = 0; i < 64; ++i) acc += wr[i] * xb[wv][i];
  float u = acc;
  float tt = tanhf(0.7978845608028654f * (u + 0.044715f * u * u * u));
  float t1 = 0.5f * u * (1.f + tt);
  tb[wv][lane] = t1;
  __syncthreads();
  float acc2 = bb2[lane];
  const float* wr2 = w2 + lane * 64;
  for (int i = 0; i < 64; ++i) acc2 += wr2[i] * tb[wv][i];
  x2[pi * 64 + lane] = xv + acc2;
}

// NHWC (bl,p,c) -> NCHW (bl,c,p) tiled transpose into d_out
__global__ __launch_bounds__(256) void transpose_out_kernel(const float* __restrict__ x2,
                                                            float* __restrict__ out) {
  int bi = blockIdx.x;  // NBL * 2 * 128
  int pt = bi & 127;
  int ct = (bi >> 7) & 1;
  int bl = bi >> 8;
  __shared__ float lds[32][33];
  int t = threadIdx.x;
  int j = t & 31, i0 = t >> 5;
  int p0 = pt << 5, c0 = ct << 5;
#pragma unroll
  for (int q = 0; q < 4; ++q) {
    int i = i0 + (q << 3);
    lds[i][j] = x2[((size_t)bl * NHW + p0 + i) * 64 + c0 + j];
  }
  __syncthreads();
#pragma unroll
  for (int q = 0; q < 4; ++q) {
    int i = i0 + (q << 3);
    out[((size_t)bl * 64 + c0 + i) * (size_t)NHW + p0 + j] = lds[j][i];
  }
}

extern "C" void kernel_launch(void* const* d_in, const int* in_sizes, int n_in,
                              void* d_out, int out_size, void* d_ws, size_t ws_size,
                              hipStream_t stream) {
  const float* img  = (const float*)d_in[0];
  const float* dz   = (const float*)d_in[1];
  const float* sg   = (const float*)d_in[2];
  const float* gn1g = (const float*)d_in[3];
  const float* gn1b = (const float*)d_in[4];
  const float* c1w  = (const float*)d_in[5];
  const float* c1b  = (const float*)d_in[6];
  const float* gn2g = (const float*)d_in[7];
  const float* gn2b = (const float*)d_in[8];
  const float* c2w  = (const float*)d_in[9];
  const float* c2b  = (const float*)d_in[10];
  const float* skw  = (const float*)d_in[11];
  const float* skb  = (const float*)d_in[12];
  const float* ln1g = (const float*)d_in[13];
  const float* ln1b = (const float*)d_in[14];
  const float* ln2g = (const float*)d_in[15];
  const float* ln2b = (const float*)d_in[16];
  const float* ipw  = (const float*)d_in[17];
  const float* dww  = (const float*)d_in[18];
  const float* dwb  = (const float*)d_in[19];
  const float* xpw  = (const float*)d_in[20];
  const float* dtw  = (const float*)d_in[21];
  const float* dtb  = (const float*)d_in[22];
  const float* Alog = (const float*)d_in[23];
  const float* Dsp  = (const float*)d_in[24];
  const float* ong  = (const float*)d_in[25];
  const float* onb  = (const float*)d_in[26];
  const float* opw  = (const float*)d_in[27];
  const float* f1w  = (const float*)d_in[28];
  const float* f1b  = (const float*)d_in[29];
  const float* f2w  = (const float*)d_in[30];
  const float* f2b  = (const float*)d_in[31];

  float* out = (float*)d_out;
  float* ws = (float*)d_ws;
  if (ws_size < F_TOTAL * sizeof(float)) return;

  float* xcat  = ws + F_XCAT;
  float* act1  = ws + F_ACT1;
  float* h1    = ws + F_H1;
  float* act2  = ws + F_ACT2;
  float* h2    = ws + F_H2;
  float* deltb = ws + F_DELTA;
  float* xres  = ws + F_XRES;
  float* xxin  = ws + F_XXIN;
  float* zbuf  = ws + F_Z;
  float* xxc   = ws + F_XXC;
  float* xdbl  = ws + F_XDBL;
  float* ysb   = ws + F_YS;
  float* ycomb = ws + F_YCOMB;
  float* x1    = ws + F_X1;
  float* x2    = ws + F_X2;
  float* stats = ws + F_STATS;
  // scan chunk arrays alias buffers that are dead during the scan
  float* chunkP  = ws + F_XXIN;   // 3,145,728 (xxin dead after dwconv)
  float* chunkH  = ws + F_YCOMB;  // 3,145,728 (ycomb written after scan)
  float* chunkHS = ws + F_X1;     // 3,145,728 (x1/x2 written after scan)

  // stage 0: instance-norm stats over image per (b,l)
  stats_kernel<<<NBL, 512, 0, stream>>>(img, NC * NHW, stats + 0, stats + 8);
  build_xcat_kernel<<<18432, 256, 0, stream>>>(img, dz, sg, stats, xcat);
  // gn1 + silu
  stats_kernel<<<NBL, 512, 0, stream>>>(xcat, NC3 * NHW, stats + 16, stats + 24);
  gn_silu_kernel<NC3><<<18432, 256, 0, stream>>>(xcat, gn1g, gn1b, stats + 16, act1);
  conv3x3_kernel<<<NBL * 64, 256, 0, stream>>>(act1, c1w, c1b, h1, NC3);
  // gn2 + silu
  stats_kernel<<<NBL, 512, 0, stream>>>(h1, NC * NHW, stats + 32, stats + 40);
  gn_silu_kernel<NC><<<6144, 256, 0, stream>>>(h1, gn2g, gn2b, stats + 32, act2);
  conv3x3_kernel<<<NBL * 64, 256, 0, stream>>>(act2, c2w, c2b, h2, NC);
  // skip 1x1 + residual + NHWC transpose
  skip_kernel<<<NBL * 64, 256, 0, stream>>>(xcat, h2, skw, skb, xres);
  // SS2D
  inproj_kernel<<<6144, 256, 0, stream>>>(xres, ln1g, ln1b, ipw, xxin, zbuf);
  dwconv_kernel<<<12288, 256, 0, stream>>>(xxin, dww, dwb, xxc);
  xdbl_kernel<<<NBL * NK * 64, 256, 0, stream>>>(xxc, xpw, xdbl);
  delta_kernel<<<49152, 256, 0, stream>>>(xdbl, dtw, dtb, deltb);
  // chunked scan
  scan_pass1_kernel<<<12288, 256, 0, stream>>>(deltb, xdbl, xxc, Alog, chunkP, chunkH);
  scan_pass2_kernel<<<192, 256, 0, stream>>>(chunkP, chunkH, chunkHS);
  scan_pass3_kernel<<<12288, 256, 0, stream>>>(deltb, xdbl, xxc, Alog, chunkHS, ysb);
  combine_kernel<<<12288, 256, 0, stream>>>(ysb, xxc, Dsp, ycomb);
  outproj_kernel<<<6144, 256, 0, stream>>>(ycomb, zbuf, ong, onb, opw, xres, x1);
  // MLP + residual
  mlp_kernel<<<6144, 256, 0, stream>>>(x1, ln2g, ln2b, f1w, f1b, f2w, f2b, x2);
  // final transpose to NCHW output
  transpose_out_kernel<<<NBL * 256, 256, 0, stream>>>(x2, out);
}

// Round 3
// 1068.357 us; speedup vs baseline: 2.8109x; 2.0059x over previous
//
#include <hip/hip_runtime.h>
#include <hip/hip_bf16.h>

// Problem constants
#define NBL 6      // B*LEN
#define NC 64
#define NC3 192
#define NHW 4096   // 64*64
#define NDI 128
#define NNS 16
#define NDR 4
#define NK 4
#define NL 4096
#define NCH 64     // scan chunks
#define SCLEN 64   // chunk length
#define NSTATE 49152  // 24 bk * 128 d * 16 n

// workspace offsets in floats
static const size_t F_XCAT  = 0;          // 6*192*4096 = 4,718,592
static const size_t F_ACT1  = 4718592;    // 4,718,592
static const size_t F_H1    = 9437184;    // 1,572,864
static const size_t F_ACT2  = 11010048;   // 1,572,864
static const size_t F_H2    = 12582912;   // 1,572,864
static const size_t F_XRES  = 14155776;   // 1,572,864
static const size_t F_XXIN  = 15728640;   // 3,145,728  (dead after dwconv -> chunkP)
static const size_t F_Z     = 18874368;   // 3,145,728
static const size_t F_XXC   = 22020096;   // 3,145,728
static const size_t F_XDBL  = 25165824;   // 6*4*36*4096 = 3,538,944
static const size_t F_YS    = 28704768;   // 12,582,912 (stats partials early, ys later)
static const size_t F_YCOMB = 41287680;   // 3,145,728  (chunkH during scan)
static const size_t F_X1    = 44433408;   // 1,572,864  (X1+X2 -> chunkHS during scan)
static const size_t F_X2    = 46006272;   // 1,572,864
static const size_t F_STATS = 47579136;   // 48
static const size_t F_TOTAL = 47579184;   // floats (~190.3 MB)

__device__ __forceinline__ float wred64(float v) {
#pragma unroll
  for (int m = 32; m; m >>= 1) v += __shfl_xor(v, m, 64);
  return v;
}

__device__ __forceinline__ float silu(float v) {
  return v / (1.f + __expf(-v));
}

__device__ __forceinline__ int map_pos(int k, int l) {
  // k0: hw order, k1: wh order, k2: hw reversed, k3: wh reversed
  if (k == 0) return l;
  if (k == 1) return ((l & 63) << 6) | (l >> 6);
  if (k == 2) return 4095 - l;
  int lp = 4095 - l;
  return ((lp & 63) << 6) | (lp >> 6);
}

// ---- two-stage per-sample mean/rstd (f64 accumulate) ----
// stage 1: grid = nsamples*32, each block reduces a 1/32 slice
__global__ __launch_bounds__(256) void stats1_kernel(const float* __restrict__ in, int n,
                                                     double* __restrict__ part) {
  int bi = blockIdx.x;
  int s = bi >> 5, j = bi & 31;
  int slice = n >> 5;
  const float4* p = (const float4*)(in + (size_t)s * n + (size_t)j * slice);
  int n4 = slice >> 2;
  double dsum = 0.0, dsq = 0.0;
  for (int i = threadIdx.x; i < n4; i += 256) {
    float4 v = p[i];
    dsum += (double)((v.x + v.y) + (v.z + v.w));
    dsq += (double)v.x * v.x + (double)v.y * v.y + (double)v.z * v.z + (double)v.w * v.w;
  }
  __shared__ double s1[256], s2[256];
  s1[threadIdx.x] = dsum; s2[threadIdx.x] = dsq;
  __syncthreads();
  for (int off = 128; off; off >>= 1) {
    if (threadIdx.x < off) { s1[threadIdx.x] += s1[threadIdx.x + off]; s2[threadIdx.x] += s2[threadIdx.x + off]; }
    __syncthreads();
  }
  if (threadIdx.x == 0) { part[2 * bi] = s1[0]; part[2 * bi + 1] = s2[0]; }
}

// stage 2: grid = nsamples, one wave combines 32 partials
__global__ __launch_bounds__(64) void stats2_kernel(const double* __restrict__ part, int n,
                                                    float* __restrict__ mean_out,
                                                    float* __restrict__ rstd_out) {
  int s = blockIdx.x;
  int lane = threadIdx.x;
  double sum = 0.0, sq = 0.0;
  if (lane < 32) { sum = part[2 * (s * 32 + lane)]; sq = part[2 * (s * 32 + lane) + 1]; }
#pragma unroll
  for (int m = 16; m; m >>= 1) { sum += __shfl_xor(sum, m, 64); sq += __shfl_xor(sq, m, 64); }
  if (lane == 0) {
    double mean = sum / n;
    double var = sq / n - mean * mean;
    mean_out[s] = (float)mean;
    rstd_out[s] = (float)(1.0 / sqrt(var + 1e-5));
  }
}

// x_cat[bl][ch][p]: ch<64 dz, 64..127 instance-normed img, 128..191 sigma
__global__ __launch_bounds__(256) void build_xcat_kernel(const float* __restrict__ img,
                                                         const float* __restrict__ dz,
                                                         const float* __restrict__ sg,
                                                         const float* __restrict__ stats,
                                                         float* __restrict__ xcat) {
  size_t gid = (size_t)blockIdx.x * 256 + threadIdx.x;  // 6*192*4096 total
  int p = gid & 4095;
  size_t r = gid >> 12;
  int ch = (int)(r % NC3);
  int bl = (int)(r / NC3);
  int b = bl / 3;  // LEN=3
  float v;
  if (ch < 64) {
    v = dz[((size_t)b * NC + ch) * NHW + p];
  } else if (ch < 128) {
    float m = stats[bl], rs = stats[8 + bl];
    v = (img[((size_t)bl * NC + (ch - 64)) * NHW + p] - m) * rs;
  } else {
    v = sg[((size_t)b * NC + (ch - 128)) * NHW + p];
  }
  xcat[gid] = v;
}

// out = silu((in - mean)*rstd*g[ch] + b[ch]), NCHW flat
template <int CCH>
__global__ __launch_bounds__(256) void gn_silu_kernel(const float* __restrict__ in,
                                                      const float* __restrict__ g,
                                                      const float* __restrict__ b,
                                                      const float* __restrict__ stats,
                                                      float* __restrict__ out) {
  size_t gid = (size_t)blockIdx.x * 256 + threadIdx.x;
  size_t r = gid >> 12;
  int ch = (int)(r % CCH);
  int bl = (int)(r / CCH);
  float m = stats[bl], rs = stats[8 + bl];
  float v = (in[gid] - m) * rs * g[ch] + b[ch];
  out[gid] = silu(v);
}

// 3x3 SAME conv, Cin->64, NCHW. grid = NBL*64 (one block per (bl, h) row).
__global__ __launch_bounds__(256) void conv3x3_kernel(const float* __restrict__ in,
                                                      const float* __restrict__ wgt,
                                                      const float* __restrict__ bias,
                                                      float* __restrict__ out, int Cin) {
  int bi = blockIdx.x;
  int bl = bi >> 6, h = bi & 63;
  const int t = threadIdx.x;
  const int oc = t & 63, w0 = (t >> 6) << 4;
  __shared__ float lds[3][64][66];
  float acc[16];
#pragma unroll
  for (int i = 0; i < 16; ++i) acc[i] = 0.f;
  const int nchunk = Cin >> 6;
  for (int cc = 0; cc < nchunk; ++cc) {
    __syncthreads();
    for (int idx = t; idx < 3 * 64 * 64; idx += 256) {
      int r = idx >> 12;
      int rem = idx & 4095;
      int ch = rem >> 6, w = rem & 63;
      int hh = h + r - 1;
      float v = 0.f;
      if (hh >= 0 && hh < 64)
        v = in[(((size_t)bl * Cin + (cc << 6) + ch) << 12) + (hh << 6) + w];
      lds[r][ch][w + 1] = v;
    }
    if (t < 192) { int r = t / 64, ch = t % 64; lds[r][ch][0] = 0.f; lds[r][ch][65] = 0.f; }
    __syncthreads();
    for (int ch = 0; ch < 64; ++ch) {
      const float* wp = wgt + ((size_t)oc * Cin + (cc << 6) + ch) * 9;
      float wv[9];
#pragma unroll
      for (int j = 0; j < 9; ++j) wv[j] = wp[j];
#pragma unroll
      for (int r = 0; r < 3; ++r) {
        float xv[18];
#pragma unroll
        for (int j = 0; j < 18; ++j) xv[j] = lds[r][ch][w0 + j];
#pragma unroll
        for (int i = 0; i < 16; ++i)
          acc[i] += wv[r * 3 + 0] * xv[i] + wv[r * 3 + 1] * xv[i + 1] + wv[r * 3 + 2] * xv[i + 2];
      }
    }
  }
  float bv = bias[oc];
  size_t ob = (((size_t)bl * 64 + oc) << 12) + (h << 6) + w0;
#pragma unroll
  for (int i = 0; i < 16; ++i) out[ob + i] = acc[i] + bv;
}

// x_res[bl][p][oc] = h2[bl][oc][p] + 1x1skip(xcat)[oc] + skb[oc]   (NHWC out)
__global__ __launch_bounds__(256) void skip_kernel(const float* __restrict__ xcat,
                                                   const float* __restrict__ h2,
                                                   const float* __restrict__ skw,
                                                   const float* __restrict__ skb,
                                                   float* __restrict__ xres) {
  int bi = blockIdx.x;
  int bl = bi >> 6, h = bi & 63;
  int t = threadIdx.x;
  int oc = t & 63, w0 = (t >> 6) << 4;
  __shared__ float lds[64][64];
  float acc[16];
#pragma unroll
  for (int i = 0; i < 16; ++i) acc[i] = 0.f;
  for (int cc = 0; cc < 3; ++cc) {
    __syncthreads();
    for (int idx = t; idx < 4096; idx += 256) {
      int ch = idx >> 6, w = idx & 63;
      lds[ch][w] = xcat[(((size_t)bl * NC3 + cc * 64 + ch) << 12) + (h << 6) + w];
    }
    __syncthreads();
    for (int ch = 0; ch < 64; ++ch) {
      float wv = skw[oc * NC3 + cc * 64 + ch];
#pragma unroll
      for (int i = 0; i < 16; ++i) acc[i] += wv * lds[ch][w0 + i];
    }
  }
  float bv = skb[oc];
  int p0 = (h << 6) + w0;
#pragma unroll
  for (int i = 0; i < 16; ++i) {
    float hv = h2[(((size_t)bl * 64 + oc) << 12) + p0 + i];
    xres[((size_t)bl * NHW + p0 + i) * 64 + oc] = acc[i] + bv + hv;
  }
}

// per position: LN(ln1) then 64->256 proj; xx part -> xxin (NHWC [pi][128]), z part -> z
__global__ __launch_bounds__(256) void inproj_kernel(const float* __restrict__ xres,
                                                     const float* __restrict__ g,
                                                     const float* __restrict__ b,
                                                     const float* __restrict__ w,
                                                     float* __restrict__ xxin,
                                                     float* __restrict__ z) {
  int wv = threadIdx.x >> 6, lane = threadIdx.x & 63;
  size_t pi = (size_t)blockIdx.x * 4 + wv;  // [0, 6*4096)
  float x = xres[pi * 64 + lane];
  float s = wred64(x);
  float s2 = wred64(x * x);
  float m = s * (1.f / 64), var = s2 * (1.f / 64) - m * m;
  float rstd = rsqrtf(var + 1e-5f);
  float xln = (x - m) * rstd * g[lane] + b[lane];
  __shared__ float xb[4][64];
  xb[wv][lane] = xln;
  __syncthreads();
  float acc[4] = {0.f, 0.f, 0.f, 0.f};
  for (int c = 0; c < 64; ++c) {
    float xv = xb[wv][c];
#pragma unroll
    for (int q = 0; q < 4; ++q) acc[q] += w[(lane + (q << 6)) * 64 + c] * xv;
  }
  xxin[(pi << 7) + lane] = acc[0];
  xxin[(pi << 7) + 64 + lane] = acc[1];
  z[(pi << 7) + lane] = acc[2];
  z[(pi << 7) + 64 + lane] = acc[3];
}

// depthwise 3x3 SAME + bias + silu on NHWC [bl][p][128]
__global__ __launch_bounds__(256) void dwconv_kernel(const float* __restrict__ xx,
                                                     const float* __restrict__ w,
                                                     const float* __restrict__ b,
                                                     float* __restrict__ out) {
  size_t gid = (size_t)blockIdx.x * 256 + threadIdx.x;  // 6*4096*128
  int d = gid & 127;
  size_t pi = gid >> 7;
  int p = (int)(pi & 4095);
  int bl = (int)(pi >> 12);
  int h = p >> 6, wq = p & 63;
  float acc = b[d];
  const float* wr = w + d * 9;
#pragma unroll
  for (int dy = -1; dy <= 1; ++dy) {
    int hh = h + dy;
    if (hh < 0 || hh >= 64) continue;
#pragma unroll
    for (int dx = -1; dx <= 1; ++dx) {
      int ww = wq + dx;
      if (ww < 0 || ww >= 64) continue;
      acc += wr[(dy + 1) * 3 + (dx + 1)] * xx[(((size_t)bl << 12) + (hh << 6) + ww) * 128 + d];
    }
  }
  out[pi * 128 + d] = silu(acc);
}

// x_dbl[bk][c][l] = sum_d xpw[k][c][d] * xs[bk][d][l]  (xs gathered via map_pos)
__global__ __launch_bounds__(256) void xdbl_kernel(const float* __restrict__ xxc,
                                                   const float* __restrict__ xpw,
                                                   float* __restrict__ xdbl) {
  int bi = blockIdx.x;               // NBL*NK*64
  int lt = bi & 63;
  int k = (bi >> 6) & 3;
  int bl = bi >> 8;
  int lbase = lt << 6;
  __shared__ float lds[64][129];
  int t = threadIdx.x;
  for (int idx = t; idx < 64 * 128; idx += 256) {
    int i = idx >> 7, d = idx & 127;
    int pos = map_pos(k, lbase + i);
    lds[i][d] = xxc[((size_t)bl * NHW + pos) * 128 + d];
  }
  __syncthreads();
  for (int oi = t; oi < 36 * 64; oi += 256) {
    int c = oi >> 6, l = oi & 63;
    const float* wrow = xpw + (k * 36 + c) * 128;
    float acc = 0.f;
    for (int d = 0; d < 128; ++d) acc += wrow[d] * lds[l][d];
    xdbl[(((size_t)(bl * 4 + k)) * 36 + c) * (size_t)NL + lbase + l] = acc;
  }
}

// ---- chunked selective scan, per-thread 16-state version ----
// grid = 24 bk * 64 chunks; block 128 (one thread per d). dt computed inline.
__global__ __launch_bounds__(128) void scan_pass1_kernel(const float* __restrict__ xdbl,
                                                         const float* __restrict__ xxc,
                                                         const float* __restrict__ dtw,
                                                         const float* __restrict__ dtb,
                                                         const float* __restrict__ Alog,
                                                         float* __restrict__ chunkP,
                                                         float* __restrict__ chunkH) {
  int bi = blockIdx.x;
  int chunk = bi & 63;
  int bk = bi >> 6;            // 0..23
  int k = bk & 3, bl = bk >> 2;
  int d = threadIdx.x;
  float4 wv = *(const float4*)(dtw + (size_t)(((k << 7) + d) << 2));
  float bias = dtb[(k << 7) + d];
  float An2[16];
  {
    const float* ar = Alog + (size_t)(((k << 7) + d) << 4);
#pragma unroll
    for (int n = 0; n < 16; ++n) An2[n] = -__expf(ar[n]) * 1.44269504f;
  }
  __shared__ float xd[SCLEN][36];
  int l0 = chunk << 6;
  for (int idx = threadIdx.x; idx < 36 * SCLEN; idx += 128) {
    int c = idx >> 6, li = idx & 63;
    xd[li][c] = xdbl[((size_t)bk * 36 + c) * (size_t)NL + l0 + li];
  }
  __syncthreads();
  const float* uB = xxc + ((size_t)bl << 19) + d;
  float h[16];
#pragma unroll
  for (int n = 0; n < 16; ++n) h[n] = 0.f;
  float sdt = 0.f;
#pragma unroll 2
  for (int li = 0; li < SCLEN; ++li) {
    int l = l0 + li;
    int pos = map_pos(k, l);
    const float4* row = (const float4*)&xd[li][0];
    float4 q0 = row[0];
    float acc = bias + wv.x * q0.x + wv.y * q0.y + wv.z * q0.z + wv.w * q0.w;
    float dt = (acc > 20.f) ? acc : log1pf(__expf(acc));
    float u = uB[(size_t)pos << 7];
    float dtu = dt * u;
    sdt += dt;
    float4 b0 = row[1], b1 = row[2], b2 = row[3], b3 = row[4];
    float Bv[16];
    Bv[0] = b0.x; Bv[1] = b0.y; Bv[2] = b0.z; Bv[3] = b0.w;
    Bv[4] = b1.x; Bv[5] = b1.y; Bv[6] = b1.z; Bv[7] = b1.w;
    Bv[8] = b2.x; Bv[9] = b2.y; Bv[10] = b2.z; Bv[11] = b2.w;
    Bv[12] = b3.x; Bv[13] = b3.y; Bv[14] = b3.z; Bv[15] = b3.w;
#pragma unroll
    for (int n = 0; n < 16; ++n) h[n] = exp2f(An2[n] * dt) * h[n] + dtu * Bv[n];
  }
  size_t base = (size_t)chunk * NSTATE + (((size_t)bk << 7) + (size_t)d) * 16;
#pragma unroll
  for (int n = 0; n < 16; ++n) {
    chunkP[base + n] = exp2f(An2[n] * sdt);
    chunkH[base + n] = h[n];
  }
}

// Pass 2: sequential combine over 64 chunks per state. grid 192 x 256.
__global__ __launch_bounds__(256) void scan_pass2_kernel(const float* __restrict__ chunkP,
                                                         const float* __restrict__ chunkH,
                                                         float* __restrict__ chunkHS) {
  size_t state = (size_t)blockIdx.x * 256 + threadIdx.x;  // < 49152
  float h = 0.f;
#pragma unroll 4
  for (int j = 0; j < NCH; ++j) {
    size_t idx = (size_t)j * NSTATE + state;
    chunkHS[idx] = h;
    h = chunkP[idx] * h + chunkH[idx];
  }
}

// Pass 3: re-run local scan seeded with h_start; emit y (no cross-lane ops).
__global__ __launch_bounds__(128) void scan_pass3_kernel(const float* __restrict__ xdbl,
                                                         const float* __restrict__ xxc,
                                                         const float* __restrict__ dtw,
                                                         const float* __restrict__ dtb,
                                                         const float* __restrict__ Alog,
                                                         const float* __restrict__ chunkHS,
                                                         float* __restrict__ ys) {
  int bi = blockIdx.x;
  int chunk = bi & 63;
  int bk = bi >> 6;
  int k = bk & 3, bl = bk >> 2;
  int d = threadIdx.x;
  float4 wv = *(const float4*)(dtw + (size_t)(((k << 7) + d) << 2));
  float bias = dtb[(k << 7) + d];
  float An2[16];
  {
    const float* ar = Alog + (size_t)(((k << 7) + d) << 4);
#pragma unroll
    for (int n = 0; n < 16; ++n) An2[n] = -__expf(ar[n]) * 1.44269504f;
  }
  __shared__ float xd[SCLEN][36];
  int l0 = chunk << 6;
  for (int idx = threadIdx.x; idx < 36 * SCLEN; idx += 128) {
    int c = idx >> 6, li = idx & 63;
    xd[li][c] = xdbl[((size_t)bk * 36 + c) * (size_t)NL + l0 + li];
  }
  __syncthreads();
  const float* uB = xxc + ((size_t)bl << 19) + d;
  float* yB = ys + ((size_t)bk << 19) + d;
  size_t base = (size_t)chunk * NSTATE + (((size_t)bk << 7) + (size_t)d) * 16;
  float h[16];
  {
    const float4* hp = (const float4*)(chunkHS + base);
    float4 h0 = hp[0], h1 = hp[1], h2 = hp[2], h3 = hp[3];
    h[0] = h0.x; h[1] = h0.y; h[2] = h0.z; h[3] = h0.w;
    h[4] = h1.x; h[5] = h1.y; h[6] = h1.z; h[7] = h1.w;
    h[8] = h2.x; h[9] = h2.y; h[10] = h2.z; h[11] = h2.w;
    h[12] = h3.x; h[13] = h3.y; h[14] = h3.z; h[15] = h3.w;
  }
#pragma unroll 2
  for (int li = 0; li < SCLEN; ++li) {
    int l = l0 + li;
    int pos = map_pos(k, l);
    const float4* row = (const float4*)&xd[li][0];
    float4 q0 = row[0];
    float acc = bias + wv.x * q0.x + wv.y * q0.y + wv.z * q0.z + wv.w * q0.w;
    float dt = (acc > 20.f) ? acc : log1pf(__expf(acc));
    float u = uB[(size_t)pos << 7];
    float dtu = dt * u;
    float4 b0 = row[1], b1 = row[2], b2 = row[3], b3 = row[4];
    float4 c0 = row[5], c1 = row[6], c2 = row[7], c3 = row[8];
    float Bv[16], Cv[16];
    Bv[0] = b0.x; Bv[1] = b0.y; Bv[2] = b0.z; Bv[3] = b0.w;
    Bv[4] = b1.x; Bv[5] = b1.y; Bv[6] = b1.z; Bv[7] = b1.w;
    Bv[8] = b2.x; Bv[9] = b2.y; Bv[10] = b2.z; Bv[11] = b2.w;
    Bv[12] = b3.x; Bv[13] = b3.y; Bv[14] = b3.z; Bv[15] = b3.w;
    Cv[0] = c0.x; Cv[1] = c0.y; Cv[2] = c0.z; Cv[3] = c0.w;
    Cv[4] = c1.x; Cv[5] = c1.y; Cv[6] = c1.z; Cv[7] = c1.w;
    Cv[8] = c2.x; Cv[9] = c2.y; Cv[10] = c2.z; Cv[11] = c2.w;
    Cv[12] = c3.x; Cv[13] = c3.y; Cv[14] = c3.z; Cv[15] = c3.w;
    float y = 0.f;
#pragma unroll
    for (int n = 0; n < 16; ++n) {
      h[n] = exp2f(An2[n] * dt) * h[n] + dtu * Bv[n];
      y += h[n] * Cv[n];
    }
    yB[(size_t)l << 7] = y;
  }
}

// ycomb[bl][p][d] = sum of 4 direction outputs (mapped) + xxc * sum_k Ds
__global__ __launch_bounds__(256) void combine_kernel(const float* __restrict__ ys,
                                                      const float* __restrict__ xxc,
                                                      const float* __restrict__ Ds,
                                                      float* __restrict__ ycomb) {
  size_t gid = (size_t)blockIdx.x * 256 + threadIdx.x;  // 6*4096*128
  int d = gid & 127;
  size_t pi = gid >> 7;
  int p = (int)(pi & 4095);
  int bl = (int)(pi >> 12);
  int h = p >> 6, w = p & 63;
  int l1 = (w << 6) | h;
  size_t base = ((size_t)bl * 4) << 12;
  float v = ys[((base + p) << 7) + d]
          + ys[((base + 4096 + l1) << 7) + d]
          + ys[((base + 2 * 4096 + (4095 - p)) << 7) + d]
          + ys[((base + 3 * 4096 + (4095 - l1)) << 7) + d];
  float ds = Ds[d] + Ds[128 + d] + Ds[256 + d] + Ds[384 + d];
  v += xxc[(pi << 7) + d] * ds;
  ycomb[(pi << 7) + d] = v;
}

// out_norm LN(128) -> *silu(z) -> out_proj 128->64 -> + x_res
__global__ __launch_bounds__(256) void outproj_kernel(const float* __restrict__ ycomb,
                                                      const float* __restrict__ z,
                                                      const float* __restrict__ ong,
                                                      const float* __restrict__ onb,
                                                      const float* __restrict__ opw,
                                                      const float* __restrict__ xres,
                                                      float* __restrict__ x1) {
  int wv = threadIdx.x >> 6, lane = threadIdx.x & 63;
  size_t pi = (size_t)blockIdx.x * 4 + wv;
  float y0 = ycomb[(pi << 7) + lane], y1 = ycomb[(pi << 7) + 64 + lane];
  float s = wred64(y0 + y1);
  float s2 = wred64(y0 * y0 + y1 * y1);
  float m = s * (1.f / 128), var = s2 * (1.f / 128) - m * m;
  float rstd = rsqrtf(var + 1e-5f);
  float z0 = z[(pi << 7) + lane], z1 = z[(pi << 7) + 64 + lane];
  float g0 = ((y0 - m) * rstd * ong[lane] + onb[lane]) * silu(z0);
  float g1 = ((y1 - m) * rstd * ong[64 + lane] + onb[64 + lane]) * silu(z1);
  __shared__ float gb[4][128];
  gb[wv][lane] = g0;
  gb[wv][64 + lane] = g1;
  __syncthreads();
  float acc = 0.f;
  const float* wrow = opw + lane * 128;
  for (int i = 0; i < 128; ++i) acc += wrow[i] * gb[wv][i];
  x1[pi * 64 + lane] = xres[pi * 64 + lane] + acc;
}

// ln2 -> fc1 -> gelu(tanh) -> fc2 -> residual; NHWC
__global__ __launch_bounds__(256) void mlp_kernel(const float* __restrict__ x1,
                                                  const float* __restrict__ g2,
                                                  const float* __restrict__ b2,
                                                  const float* __restrict__ w1,
                                                  const float* __restrict__ bb1,
                                                  const float* __restrict__ w2,
                                                  const float* __restrict__ bb2,
                                                  float* __restrict__ x2) {
  int wv = threadIdx.x >> 6, lane = threadIdx.x & 63;
  size_t pi = (size_t)blockIdx.x * 4 + wv;
  float xv = x1[pi * 64 + lane];
  float s = wred64(xv), s2 = wred64(xv * xv);
  float m = s * (1.f / 64), var = s2 * (1.f / 64) - m * m;
  float rstd = rsqrtf(var + 1e-5f);
  float xm = (xv - m) * rstd * g2[lane] + b2[lane];
  __shared__ float xb[4][64], tb[4][64];
  xb[wv][lane] = xm;
  __syncthreads();
  float acc = bb1[lane];
  const float* wr = w1 + lane * 64;
  for (int i = 0; i < 64; ++i) acc += wr[i] * xb[wv][i];
  float u = acc;
  float tt = tanhf(0.7978845608028654f * (u + 0.044715f * u * u * u));
  float t1 = 0.5f * u * (1.f + tt);
  tb[wv][lane] = t1;
  __syncthreads();
  float acc2 = bb2[lane];
  const float* wr2 = w2 + lane * 64;
  for (int i = 0; i < 64; ++i) acc2 += wr2[i] * tb[wv][i];
  x2[pi * 64 + lane] = xv + acc2;
}

// NHWC (bl,p,c) -> NCHW (bl,c,p) tiled transpose into d_out
__global__ __launch_bounds__(256) void transpose_out_kernel(const float* __restrict__ x2,
                                                            float* __restrict__ out) {
  int bi = blockIdx.x;  // NBL * 2 * 128
  int pt = bi & 127;
  int ct = (bi >> 7) & 1;
  int bl = bi >> 8;
  __shared__ float lds[32][33];
  int t = threadIdx.x;
  int j = t & 31, i0 = t >> 5;
  int p0 = pt << 5, c0 = ct << 5;
#pragma unroll
  for (int q = 0; q < 4; ++q) {
    int i = i0 + (q << 3);
    lds[i][j] = x2[((size_t)bl * NHW + p0 + i) * 64 + c0 + j];
  }
  __syncthreads();
#pragma unroll
  for (int q = 0; q < 4; ++q) {
    int i = i0 + (q << 3);
    out[((size_t)bl * 64 + c0 + i) * (size_t)NHW + p0 + j] = lds[j][i];
  }
}

extern "C" void kernel_launch(void* const* d_in, const int* in_sizes, int n_in,
                              void* d_out, int out_size, void* d_ws, size_t ws_size,
                              hipStream_t stream) {
  const float* img  = (const float*)d_in[0];
  const float* dz   = (const float*)d_in[1];
  const float* sg   = (const float*)d_in[2];
  const float* gn1g = (const float*)d_in[3];
  const float* gn1b = (const float*)d_in[4];
  const float* c1w  = (const float*)d_in[5];
  const float* c1b  = (const float*)d_in[6];
  const float* gn2g = (const float*)d_in[7];
  const float* gn2b = (const float*)d_in[8];
  const float* c2w  = (const float*)d_in[9];
  const float* c2b  = (const float*)d_in[10];
  const float* skw  = (const float*)d_in[11];
  const float* skb  = (const float*)d_in[12];
  const float* ln1g = (const float*)d_in[13];
  const float* ln1b = (const float*)d_in[14];
  const float* ln2g = (const float*)d_in[15];
  const float* ln2b = (const float*)d_in[16];
  const float* ipw  = (const float*)d_in[17];
  const float* dww  = (const float*)d_in[18];
  const float* dwb  = (const float*)d_in[19];
  const float* xpw  = (const float*)d_in[20];
  const float* dtw  = (const float*)d_in[21];
  const float* dtb  = (const float*)d_in[22];
  const float* Alog = (const float*)d_in[23];
  const float* Dsp  = (const float*)d_in[24];
  const float* ong  = (const float*)d_in[25];
  const float* onb  = (const float*)d_in[26];
  const float* opw  = (const float*)d_in[27];
  const float* f1w  = (const float*)d_in[28];
  const float* f1b  = (const float*)d_in[29];
  const float* f2w  = (const float*)d_in[30];
  const float* f2b  = (const float*)d_in[31];

  float* out = (float*)d_out;
  float* ws = (float*)d_ws;
  if (ws_size < F_TOTAL * sizeof(float)) return;

  float* xcat  = ws + F_XCAT;
  float* act1  = ws + F_ACT1;
  float* h1    = ws + F_H1;
  float* act2  = ws + F_ACT2;
  float* h2    = ws + F_H2;
  float* xres  = ws + F_XRES;
  float* xxin  = ws + F_XXIN;
  float* zbuf  = ws + F_Z;
  float* xxc   = ws + F_XXC;
  float* xdbl  = ws + F_XDBL;
  float* ysb   = ws + F_YS;
  float* ycomb = ws + F_YCOMB;
  float* x1    = ws + F_X1;
  float* x2    = ws + F_X2;
  float* stats = ws + F_STATS;
  // scan chunk arrays alias buffers that are dead during the scan
  float* chunkP  = ws + F_XXIN;   // 3,145,728 (xxin dead after dwconv)
  float* chunkH  = ws + F_YCOMB;  // 3,145,728 (ycomb written after scan)
  float* chunkHS = ws + F_X1;     // 3,145,728 (x1/x2 written after scan)
  // stats partials live in the (still-dead) YS region
  double* part = (double*)(ws + F_YS);

  // stage 0: instance-norm stats over image per (b,l)
  stats1_kernel<<<NBL * 32, 256, 0, stream>>>(img, NC * NHW, part);
  stats2_kernel<<<NBL, 64, 0, stream>>>(part, NC * NHW, stats + 0, stats + 8);
  build_xcat_kernel<<<18432, 256, 0, stream>>>(img, dz, sg, stats, xcat);
  // gn1 + silu
  stats1_kernel<<<NBL * 32, 256, 0, stream>>>(xcat, NC3 * NHW, part);
  stats2_kernel<<<NBL, 64, 0, stream>>>(part, NC3 * NHW, stats + 16, stats + 24);
  gn_silu_kernel<NC3><<<18432, 256, 0, stream>>>(xcat, gn1g, gn1b, stats + 16, act1);
  conv3x3_kernel<<<NBL * 64, 256, 0, stream>>>(act1, c1w, c1b, h1, NC3);
  // gn2 + silu
  stats1_kernel<<<NBL * 32, 256, 0, stream>>>(h1, NC * NHW, part);
  stats2_kernel<<<NBL, 64, 0, stream>>>(part, NC * NHW, stats + 32, stats + 40);
  gn_silu_kernel<NC><<<6144, 256, 0, stream>>>(h1, gn2g, gn2b, stats + 32, act2);
  conv3x3_kernel<<<NBL * 64, 256, 0, stream>>>(act2, c2w, c2b, h2, NC);
  // skip 1x1 + residual + NHWC transpose
  skip_kernel<<<NBL * 64, 256, 0, stream>>>(xcat, h2, skw, skb, xres);
  // SS2D
  inproj_kernel<<<6144, 256, 0, stream>>>(xres, ln1g, ln1b, ipw, xxin, zbuf);
  dwconv_kernel<<<12288, 256, 0, stream>>>(xxin, dww, dwb, xxc);
  xdbl_kernel<<<NBL * NK * 64, 256, 0, stream>>>(xxc, xpw, xdbl);
  // chunked scan (dt computed inline; no delta buffer)
  scan_pass1_kernel<<<24 * 64, 128, 0, stream>>>(xdbl, xxc, dtw, dtb, Alog, chunkP, chunkH);
  scan_pass2_kernel<<<192, 256, 0, stream>>>(chunkP, chunkH, chunkHS);
  scan_pass3_kernel<<<24 * 64, 128, 0, stream>>>(xdbl, xxc, dtw, dtb, Alog, chunkHS, ysb);
  combine_kernel<<<12288, 256, 0, stream>>>(ysb, xxc, Dsp, ycomb);
  outproj_kernel<<<6144, 256, 0, stream>>>(ycomb, zbuf, ong, onb, opw, xres, x1);
  // MLP + residual
  mlp_kernel<<<6144, 256, 0, stream>>>(x1, ln2g, ln2b, f1w, f1b, f2w, f2b, x2);
  // final transpose to NCHW output
  transpose_out_kernel<<<NBL * 256, 256, 0, stream>>>(x2, out);
}